// Round 9
// baseline (264.387 us; speedup 1.0000x reference)
//
#include <hip/hip_runtime.h>
#include <cstdint>
#include <cstddef>

typedef unsigned int uint;
typedef unsigned short ushort;

#define DEVFN __device__ __forceinline__

DEVFN float bf2f(uint h) { return __uint_as_float(h << 16); }
DEVFN ushort f2bf(float x) {
  uint u = __float_as_uint(x);
  u = (u + 0x7FFFu + ((u >> 16) & 1u)) >> 16;
  return (ushort)u;
}
DEVFN float sigmoidf(float x) { return 1.0f / (1.0f + __expf(-x)); }

// ---------------------------------------------------------------------------
// Kernel 1: y_h = h_en_w @ x, y_z = z_en_w @ x  (per pixel 64x64 matvec)
// x NCHW fp32 -> ypack NHWC (dword per (pix,c): lo16 bf16(y_h), hi16 bf16(y_z))
// PLUS fused per-tile pooling partials (fp32): part[b][tile][stat][c],
// stat: 0=sum_h 1=max_h 2=sum_z 3=max_z   (no atomics -> no zero-init kernel)
// grid 512 = b(2) x tile(256); block 256; each block: 64 pixels, all 64 outputs
// ---------------------------------------------------------------------------
__global__ __launch_bounds__(256) void k_conv(const float* __restrict__ x,
                                              const float* __restrict__ wh,
                                              const float* __restrict__ wz,
                                              uint* __restrict__ ypack,
                                              float* __restrict__ part) {
  __shared__ __align__(16) float xt[64][66];
  __shared__ __align__(16) float wls[2][64][64];  // [hz][c][o] transposed
  const int tid = threadIdx.x;
  const int b = blockIdx.x >> 8;
  const int tile = blockIdx.x & 255;
  const int pix0 = tile * 64;

  for (int idx = tid; idx < 4096; idx += 256) {
    int o = idx >> 6, c = idx & 63;
    wls[0][c][o] = wh[idx];
    wls[1][c][o] = wz[idx];
  }
  const float* xb = x + ((size_t)b << 20);  // b * 64*16384
  for (int idx = tid; idx < 4096; idx += 256) {
    int c = idx >> 6, p = idx & 63;
    xt[c][p] = xb[c * 16384 + pix0 + p];
  }
  __syncthreads();

  const int p = tid & 63, og = tid >> 6, o0 = og * 16;
  float fh[16], fz[16];
#pragma unroll
  for (int j = 0; j < 16; ++j) { fh[j] = 0.0f; fz[j] = 0.0f; }

  for (int c = 0; c < 64; ++c) {
    float xv = xt[c][p];
    const float4* whp = (const float4*)&wls[0][c][o0];
    const float4* wzp = (const float4*)&wls[1][c][o0];
#pragma unroll
    for (int jj = 0; jj < 4; ++jj) {
      float4 a = whp[jj], bb = wzp[jj];
      fh[jj * 4 + 0] += xv * a.x; fh[jj * 4 + 1] += xv * a.y;
      fh[jj * 4 + 2] += xv * a.z; fh[jj * 4 + 3] += xv * a.w;
      fz[jj * 4 + 0] += xv * bb.x; fz[jj * 4 + 1] += xv * bb.y;
      fz[jj * 4 + 2] += xv * bb.z; fz[jj * 4 + 3] += xv * bb.w;
    }
  }
  uint* orow = ypack + ((size_t)(b * 16384 + pix0 + p)) * 64 + o0;
#pragma unroll
  for (int jj = 0; jj < 4; ++jj) {
    uint4 pk;
    pk.x = (uint)f2bf(fh[jj * 4 + 0]) | ((uint)f2bf(fz[jj * 4 + 0]) << 16);
    pk.y = (uint)f2bf(fh[jj * 4 + 1]) | ((uint)f2bf(fz[jj * 4 + 1]) << 16);
    pk.z = (uint)f2bf(fh[jj * 4 + 2]) | ((uint)f2bf(fz[jj * 4 + 2]) << 16);
    pk.w = (uint)f2bf(fh[jj * 4 + 3]) | ((uint)f2bf(fz[jj * 4 + 3]) << 16);
    ((uint4*)orow)[jj] = pk;
  }

  // ---- fused pooling partials (fp32, exact y before bf16 rounding) ----
  __syncthreads();  // done reading xt / wls everywhere
  float* xtA = &xt[0][0];        // [o*66 + p] holds y_h
  float* ztA = &wls[0][0][0];    // [o*66 + p] holds y_z (4224 <= 8192 floats)
#pragma unroll
  for (int j = 0; j < 16; ++j) {
    xtA[(o0 + j) * 66 + p] = fh[j];
    ztA[(o0 + j) * 66 + p] = fz[j];
  }
  __syncthreads();
  if (tid < 128) {
    const int o = tid & 63;
    const float* src = (tid < 64) ? xtA : ztA;
    float sm = 0.0f, mx = -1e30f;
#pragma unroll 8
    for (int pp = 0; pp < 64; ++pp) {
      float v = src[o * 66 + pp];
      sm += v; mx = fmaxf(mx, v);
    }
    float* pb = part + ((size_t)(b * 256 + tile) * 4) * 64;
    const int st = (tid < 64) ? 0 : 2;
    pb[st * 64 + o] = sm;
    pb[(st + 1) * 64 + o] = mx;
  }
}

// ---------------------------------------------------------------------------
// Kernel 2: SE attention scalars.  attnb layout: [hz][b][i*64+c], hz=0 h, 1 z
// grid 4 = hz(2) x b(2); block 256.  Reduces part[] (512 KB) itself.
// ---------------------------------------------------------------------------
__global__ __launch_bounds__(256) void k_attn(const float* __restrict__ part,
                       const float* __restrict__ hsw, const float* __restrict__ zsw,
                       const float* __restrict__ hew, const float* __restrict__ zew,
                       float* __restrict__ attnb) {
  __shared__ float psum[4][64];
  __shared__ float pmax[4][64];
  __shared__ float pooled[128];
  __shared__ float hdn[128];
  const int tid = threadIdx.x;
  const int hz = blockIdx.x >> 1, bb = blockIdx.x & 1;
  const int g = tid >> 6, c = tid & 63;

  // phase A: reduce 256 tile-partials -> pooled[128] (mean | max)
  {
    float sm = 0.0f, mx = -1e30f;
    const float* pb = part + ((size_t)(bb * 256 + g * 64) * 4) * 64;
    for (int tt = 0; tt < 64; ++tt) {
      sm += pb[(size_t)tt * 256 + 2 * hz * 64 + c];
      mx = fmaxf(mx, pb[(size_t)tt * 256 + (2 * hz + 1) * 64 + c]);
    }
    psum[g][c] = sm; pmax[g][c] = mx;
  }
  __syncthreads();
  if (tid < 64) {
    float sm = psum[0][c] + psum[1][c] + psum[2][c] + psum[3][c];
    float mx = fmaxf(fmaxf(pmax[0][c], pmax[1][c]), fmaxf(pmax[2][c], pmax[3][c]));
    pooled[c] = sm * (1.0f / 16384.0f);
    pooled[64 + c] = mx;
  }
  __syncthreads();
  // phase B: hidden = relu(s_w @ pooled)
  if (tid < 128) {
    const float* sw = hz ? zsw : hsw;
    float acc = 0.0f;
    for (int cc = 0; cc < 128; ++cc) acc += pooled[cc] * sw[tid * 128 + cc];
    hdn[tid] = fmaxf(acc, 0.0f);
  }
  __syncthreads();
  // phase C: attn = sigmoid(gconv(e_w, hidden))
  const float* ew = hz ? zew : hew;
  for (int o2 = tid; o2 < 512; o2 += 256) {
    const int gb = (o2 >> 6) * 16;
    float acc = 0.0f;
#pragma unroll
    for (int vv = 0; vv < 16; ++vv) acc += hdn[gb + vv] * ew[o2 * 16 + vv];
    attnb[(hz * 2 + bb) * 512 + o2] = sigmoidf(acc);
  }
}

// ---------------------------------------------------------------------------
// Kernel 3: all 8 directional GRU scans. One wave per chain; lane = channel.
// Depth-8 software-pipelined loads (wave-uniform guards; no OOB loads).
// waves: dirs 0..3: 4*2*255 = 2040 ; dirs 4..7: 4*2*128 = 1024 ; total 3064
// grid 766 x 256 (4 waves/block)
// ---------------------------------------------------------------------------
__global__ __launch_bounds__(256) void k_scan(const uint* __restrict__ ypack,
                                              const float* __restrict__ attnb,
                                              const float* __restrict__ h0,
                                              ushort* __restrict__ xcat) {
  const int wid = blockIdx.x * 4 + (threadIdx.x >> 6);
  const int lane = threadIdx.x & 63;
  int i, b, s;
  if (wid < 2040) {
    i = wid / 510;
    int r = wid - i * 510;
    b = (r >= 255) ? 1 : 0;
    s = r - b * 255;
  } else {
    int w2 = wid - 2040;
    i = 4 + (w2 >> 8);
    int r = w2 & 255;
    b = r >> 7;
    s = r & 127;
  }
  int h0s, w0s, dh, dw, L;
  switch (i) {
    case 0: dh = 1;  dw = 1;
      if (s < 128) { h0s = s; w0s = 0; L = 128 - s; } else { h0s = 0; w0s = s - 127; L = 255 - s; }
      break;
    case 1: dh = 1;  dw = -1;
      if (s < 128) { h0s = 0; w0s = s; L = s + 1; } else { h0s = s - 127; w0s = 127; L = 255 - s; }
      break;
    case 2: dh = -1; dw = 1;
      if (s < 128) { h0s = s; w0s = 0; L = s + 1; } else { h0s = 127; w0s = s - 127; L = 255 - s; }
      break;
    case 3: dh = -1; dw = -1;
      if (s < 128) { h0s = 127; w0s = s; L = s + 1; } else { h0s = s - 128; w0s = 127; L = s - 127; }
      break;
    case 4: dh = 1;  dw = 0;  h0s = 0;   w0s = s; L = 128; break;
    case 5: dh = -1; dw = 0;  h0s = 127; w0s = s; L = 128; break;
    case 6: dh = 0;  dw = 1;  h0s = s;   w0s = 0; L = 128; break;
    default: dh = 0; dw = -1; h0s = s;   w0s = 127; L = 128; break;
  }
  const float ah = attnb[b * 512 + i * 64 + lane];          // hz = 0
  const float az = attnb[1024 + b * 512 + i * 64 + lane];   // hz = 1
  float hp = h0[i * 64 + lane];

  const int pos = b * 16384 + h0s * 128 + w0s;
  const int dstep = dh * 128 + dw;
  const uint* yp = ypack + (size_t)pos * 64 + lane;
  ushort* xp = xcat + (size_t)pos * 512 + i * 64 + lane;
  const ptrdiff_t ystep = (ptrdiff_t)dstep * 64;
  const ptrdiff_t xstep = (ptrdiff_t)dstep * 512;

#define PROC1(u) { float yh = bf2f((u) & 0xffffu), yz = bf2f((u) >> 16); \
                   float zt = sigmoidf(yz * az);                          \
                   hp = fmaf(zt, fmaf(yh, ah, -hp), hp);                  \
                   *xp = f2bf(hp); xp += xstep; }

  uint c0 = 0, c1 = 0, c2 = 0, c3 = 0, c4 = 0, c5 = 0, c6 = 0, c7 = 0;
  c0 = yp[0];                                   // L >= 1 always
  if (1 < L) c1 = yp[ystep];
  if (2 < L) c2 = yp[2 * ystep];
  if (3 < L) c3 = yp[3 * ystep];
  if (4 < L) c4 = yp[4 * ystep];
  if (5 < L) c5 = yp[5 * ystep];
  if (6 < L) c6 = yp[6 * ystep];
  if (7 < L) c7 = yp[7 * ystep];

  for (int base = 0; base < L; base += 8) {
    uint b0 = c0, b1 = c1, b2 = c2, b3 = c3, b4 = c4, b5 = c5, b6 = c6, b7 = c7;
    const uint* ypn = yp + (ptrdiff_t)(base + 8) * ystep;
    if (base + 8 < L) {
      c0 = ypn[0];
      if (base + 9  < L) c1 = ypn[ystep];
      if (base + 10 < L) c2 = ypn[2 * ystep];
      if (base + 11 < L) c3 = ypn[3 * ystep];
      if (base + 12 < L) c4 = ypn[4 * ystep];
      if (base + 13 < L) c5 = ypn[5 * ystep];
      if (base + 14 < L) c6 = ypn[6 * ystep];
      if (base + 15 < L) c7 = ypn[7 * ystep];
    }
    PROC1(b0);
    if (base + 1 < L) PROC1(b1);
    if (base + 2 < L) PROC1(b2);
    if (base + 3 < L) PROC1(b3);
    if (base + 4 < L) PROC1(b4);
    if (base + 5 < L) PROC1(b5);
    if (base + 6 < L) PROC1(b6);
    if (base + 7 < L) PROC1(b7);
  }
#undef PROC1
}

// ---------------------------------------------------------------------------
// Kernel 4: per-pixel sort(512) + grouped-conv attention + weighted sum.
// One wave per pixel PAIR (2-pixel ILP: two independent shuffle chains
// interleave -> hides ds_bpermute latency even at low occupancy).
// element e = lane*8 + r. grid 2048 = b(2) x tile(1024), block 256
// (4 waves x 2 pairs each). w4 weights in LDS (bf16x2, lane-major).
// tb1 rows are WAVE-PRIVATE; same-wave DS ordering -> no in-loop barriers
// (pattern hardware-validated rounds 4/7). LDS 33024 B -> 4 blocks/CU.
// Plain __launch_bounds__(256): no waves-per-EU pin (round-7 evidence:
// ",2" pinned occupancy to 21%).
// ---------------------------------------------------------------------------
__global__ __launch_bounds__(256) void k_final(const ushort* __restrict__ xcat,
                                               const float* __restrict__ a_w1,
                                               const float* __restrict__ a_w2,
                                               const float* __restrict__ a_w3,
                                               const float* __restrict__ a_w4,
                                               float* __restrict__ out) {
  __shared__ __align__(16) float w1s[128 * 32];
  __shared__ uint w4p[32 * 64];     // [rr*4+kp][lane] packed bf16x2
  __shared__ float tb1[4][2][128];
  __shared__ __align__(16) float otile[16][68];

  const int tid = threadIdx.x;
  const int lane = tid & 63;
  const int wslot = tid >> 6;
  const int b = blockIdx.x >> 10;
  const int tile = blockIdx.x & 1023;
  const int pix0 = tile * 16;

  // stage a_w1 with swizzle: slot = o*32 + ((ci + (o>>2)) & 31)
  for (int idx = tid; idx < 4096; idx += 256) {
    int o = idx >> 5, ci = idx & 31;
    w1s[o * 32 + ((ci + (o >> 2)) & 31)] = a_w1[idx];
  }
  // stage a_w4 as bf16x2, lane-major
  for (int idx = tid; idx < 2048; idx += 256) {
    int rk2 = idx >> 6, l = idx & 63;
    int rr = rk2 >> 2, kp = rk2 & 3;
    const float* src = a_w4 + ((l * 8 + rr) * 8 + 2 * kp);
    w4p[rk2 * 64 + l] = (uint)f2bf(src[0]) | ((uint)f2bf(src[1]) << 16);
  }

  // per-lane register weights for gconv2/3
  float w2a[8], w2b[8], w3a[8], w3b[8];
  {
    const float4* p;
    p = (const float4*)(a_w2 + lane * 8);        ((float4*)w2a)[0] = p[0]; ((float4*)w2a)[1] = p[1];
    p = (const float4*)(a_w2 + 512 + lane * 8);  ((float4*)w2b)[0] = p[0]; ((float4*)w2b)[1] = p[1];
    p = (const float4*)(a_w3 + lane * 8);        ((float4*)w3a)[0] = p[0]; ((float4*)w3a)[1] = p[1];
    p = (const float4*)(a_w3 + 512 + lane * 8);  ((float4*)w3b)[0] = p[0]; ((float4*)w3b)[1] = p[1];
  }
  __syncthreads();

  const int q = lane >> 2, m4 = lane & 3;
  const int base1 = 64 * ((lane >> 3) & 1) + (lane >> 4);
  const int base3 = 64 * ((lane >> 2) & 1) + (lane >> 3);

  for (int itp = 0; itp < 2; ++itp) {
    const int pxA = wslot * 4 + itp * 2;   // this wave's pixel pair
    const int pix = pix0 + pxA;

    float v[2][8], s[2][8];
    {
      const ushort* basep = xcat + (((size_t)(b * 16384 + pix)) << 9) + lane * 8;
#pragma unroll
      for (int p = 0; p < 2; ++p) {
        const uint4 pk = *(const uint4*)(basep + p * 512);
        v[p][0] = bf2f(pk.x & 0xffffu); v[p][1] = bf2f(pk.x >> 16);
        v[p][2] = bf2f(pk.y & 0xffffu); v[p][3] = bf2f(pk.y >> 16);
        v[p][4] = bf2f(pk.z & 0xffffu); v[p][5] = bf2f(pk.z >> 16);
        v[p][6] = bf2f(pk.w & 0xffffu); v[p][7] = bf2f(pk.w >> 16);
#pragma unroll
        for (int r = 0; r < 8; ++r) s[p][r] = v[p][r];
      }
    }

    // ---- bitonic sort x2 (interleaved), ascending, 512 elems, e = lane*8+r --
    // direction of element e at stage k: asc iff (e & k) == 0.
    // e&k for k>=8 is a LANE bit ((lane & (k>>3))); only for k<8 is it an r bit.
#pragma unroll
    for (int k = 2; k <= 512; k <<= 1) {
#pragma unroll
      for (int j = k >> 1; j >= 1; j >>= 1) {
        if (j >= 8) {
          const int m = j >> 3;
          const bool upper = (lane & m) != 0;
          const bool asc = (lane & (k >> 3)) == 0;  // k=512 -> lane&64==0 -> true
          const bool takeMin = (upper != asc);
#pragma unroll
          for (int p = 0; p < 2; ++p) {
#pragma unroll
            for (int r = 0; r < 8; ++r) {
              float o = __shfl_xor(s[p][r], m, 64);
              float mn = fminf(s[p][r], o), mx = fmaxf(s[p][r], o);
              s[p][r] = takeMin ? mn : mx;
            }
          }
        } else if (k < 8) {  // k=2,4: direction from r&k (k=8 must NOT land here)
#pragma unroll
          for (int p = 0; p < 2; ++p) {
#pragma unroll
            for (int r = 0; r < 8; ++r) {
              if ((r & j) == 0) {
                int r2 = r | j;
                float mn = fminf(s[p][r], s[p][r2]), mx = fmaxf(s[p][r], s[p][r2]);
                if ((r & k) == 0) { s[p][r] = mn; s[p][r2] = mx; }
                else { s[p][r] = mx; s[p][r2] = mn; }
              }
            }
          }
        } else {  // j<8, k>=8: direction from lane bit (k=8 -> lane&1)
          const bool asc = (lane & (k >> 3)) == 0;
#pragma unroll
          for (int p = 0; p < 2; ++p) {
#pragma unroll
            for (int r = 0; r < 8; ++r) {
              if ((r & j) == 0) {
                int r2 = r | j;
                float mn = fminf(s[p][r], s[p][r2]), mx = fmaxf(s[p][r], s[p][r2]);
                s[p][r] = asc ? mn : mx;
                s[p][r2] = asc ? mx : mn;
              }
            }
          }
        }
      }
    }

    // ---- gconv1 (1024 -> 128, groups 32): quad-cooperative, shared W reads --
    float pa[2][4], pb[2][4];
#pragma unroll
    for (int u = 0; u < 4; ++u) {
      const float* wV = &w1s[(4 * q + u) * 32];
      const float* wS = &w1s[(64 + 4 * q + u) * 32];
#pragma unroll
      for (int p = 0; p < 2; ++p) {
        float aV = 0.0f, aS = 0.0f;
#pragma unroll
        for (int r = 0; r < 8; ++r) {
          const int ci = m4 * 8 + r;
          aV += v[p][r] * wV[(ci + q) & 31];
          aS += s[p][r] * wS[(ci + q + 16) & 31];
        }
        pa[p][u] = aV; pb[p][u] = aS;
      }
    }
#pragma unroll
    for (int p = 0; p < 2; ++p) {
#pragma unroll
      for (int u = 0; u < 4; ++u) {
        pa[p][u] += __shfl_xor(pa[p][u], 1, 64);
        pa[p][u] += __shfl_xor(pa[p][u], 2, 64);
        pb[p][u] += __shfl_xor(pb[p][u], 1, 64);
        pb[p][u] += __shfl_xor(pb[p][u], 2, 64);
      }
    }
#pragma unroll
    for (int p = 0; p < 2; ++p) {
      const float t1a = (m4 == 0) ? pa[p][0] : (m4 == 1) ? pa[p][1]
                       : (m4 == 2) ? pa[p][2] : pa[p][3];
      const float t1b = (m4 == 0) ? pb[p][0] : (m4 == 1) ? pb[p][1]
                       : (m4 == 2) ? pb[p][2] : pb[p][3];
      tb1[wslot][p][lane] = t1a;
      tb1[wslot][p][64 + lane] = t1b;
    }

    // ---- gconv2 (shuffle16 then 128 -> 128, groups 16): read both, then write
    float a2[2], b2[2];
#pragma unroll
    for (int p = 0; p < 2; ++p) {
      a2[p] = 0.0f; b2[p] = 0.0f;
#pragma unroll
      for (int kk = 0; kk < 8; ++kk) {
        a2[p] += tb1[wslot][p][base1 + 8 * kk] * w2a[kk];
        b2[p] += tb1[wslot][p][base1 + 8 * kk + 4] * w2b[kk];
      }
    }
#pragma unroll
    for (int p = 0; p < 2; ++p) {
      tb1[wslot][p][lane] = a2[p];
      tb1[wslot][p][64 + lane] = b2[p];
    }

    // ---- gconv3 + relu ----
    float a3[2], b3[2];
#pragma unroll
    for (int p = 0; p < 2; ++p) {
      a3[p] = 0.0f; b3[p] = 0.0f;
#pragma unroll
      for (int kk = 0; kk < 8; ++kk) {
        a3[p] += tb1[wslot][p][base1 + 8 * kk] * w3a[kk];
        b3[p] += tb1[wslot][p][base1 + 8 * kk + 4] * w3b[kk];
      }
    }
#pragma unroll
    for (int p = 0; p < 2; ++p) {
      tb1[wslot][p][lane] = fmaxf(a3[p], 0.0f);
      tb1[wslot][p][64 + lane] = fmaxf(b3[p], 0.0f);
    }

    // ---- gconv4 (128 -> 512, groups 16) + sigmoid + weighted channel-sum ----
    float in4[2][8];
#pragma unroll
    for (int p = 0; p < 2; ++p)
#pragma unroll
      for (int kk = 0; kk < 8; ++kk) in4[p][kk] = tb1[wslot][p][base3 + 8 * kk];

    float prod[2][8];
#pragma unroll
    for (int rr = 0; rr < 8; ++rr) {
      float accA = 0.0f, accB = 0.0f;
#pragma unroll
      for (int kp = 0; kp < 4; ++kp) {
        uint pw = w4p[(rr * 4 + kp) * 64 + lane];
        float wlo = __uint_as_float(pw << 16);
        float whi = __uint_as_float(pw & 0xffff0000u);
        accA += in4[0][2 * kp] * wlo + in4[0][2 * kp + 1] * whi;
        accB += in4[1][2 * kp] * wlo + in4[1][2 * kp + 1] * whi;
      }
      prod[0][rr] = v[0][rr] * sigmoidf(accA);
      prod[1][rr] = v[1][rr] * sigmoidf(accB);
    }
#pragma unroll
    for (int p = 0; p < 2; ++p)
#pragma unroll
      for (int rr = 0; rr < 8; ++rr) {
        prod[p][rr] += __shfl_xor(prod[p][rr], 8, 64);
        prod[p][rr] += __shfl_xor(prod[p][rr], 16, 64);
        prod[p][rr] += __shfl_xor(prod[p][rr], 32, 64);
      }
    if (lane < 8) {
#pragma unroll
      for (int p = 0; p < 2; ++p) {
        float4* dst = (float4*)&otile[pxA + p][lane * 8];
        dst[0] = make_float4(prod[p][0], prod[p][1], prod[p][2], prod[p][3]);
        dst[1] = make_float4(prod[p][4], prod[p][5], prod[p][6], prod[p][7]);
      }
    }
  }
  __syncthreads();

  // coalesced NCHW store: out[b][c][pix0 + px]
  for (int idx = tid; idx < 1024; idx += 256) {
    int px = idx & 15, c = idx >> 4;
    out[(((size_t)(b * 64 + c)) << 14) + pix0 + px] = otile[px][c];
  }
}

// ---------------------------------------------------------------------------
extern "C" void kernel_launch(void* const* d_in, const int* in_sizes, int n_in,
                              void* d_out, int out_size, void* d_ws, size_t ws_size,
                              hipStream_t stream) {
  const float* x      = (const float*)d_in[0];
  const float* h0     = (const float*)d_in[1];
  const float* h_en_w = (const float*)d_in[2];
  const float* h_s_w  = (const float*)d_in[3];
  const float* h_e_w  = (const float*)d_in[4];
  const float* z_en_w = (const float*)d_in[5];
  const float* z_s_w  = (const float*)d_in[6];
  const float* z_e_w  = (const float*)d_in[7];
  const float* a_w1   = (const float*)d_in[8];
  const float* a_w2   = (const float*)d_in[9];
  const float* a_w3   = (const float*)d_in[10];
  const float* a_w4   = (const float*)d_in[11];
  float* out = (float*)d_out;

  char* ws = (char*)d_ws;
  uint*   ypack = (uint*)ws;                                   // 8 MB
  ushort* xcat  = (ushort*)(ws + ((size_t)8 << 20));           // 32 MB
  float*  part  = (float*)(ws + ((size_t)40 << 20));           // 512 KB
  float*  attnb = (float*)(ws + ((size_t)40 << 20) + (1u << 20));  // 2048 f

  hipLaunchKernelGGL(k_conv, dim3(512), dim3(256), 0, stream, x, h_en_w, z_en_w,
                     ypack, part);
  hipLaunchKernelGGL(k_attn, dim3(4), dim3(256), 0, stream, part, h_s_w, z_s_w,
                     h_e_w, z_e_w, attnb);
  hipLaunchKernelGGL(k_scan, dim3(766), dim3(256), 0, stream, ypack, attnb, h0, xcat);
  hipLaunchKernelGGL(k_final, dim3(2048), dim3(256), 0, stream, xcat, a_w1, a_w2, a_w3,
                     a_w4, out);
}

// Round 10
// 222.375 us; speedup vs baseline: 1.1889x; 1.1889x over previous
//
#include <hip/hip_runtime.h>
#include <cstdint>
#include <cstddef>

typedef unsigned int uint;
typedef unsigned short ushort;

#define DEVFN __device__ __forceinline__

DEVFN float bf2f(uint h) { return __uint_as_float(h << 16); }
DEVFN ushort f2bf(float x) {
  uint u = __float_as_uint(x);
  u = (u + 0x7FFFu + ((u >> 16) & 1u)) >> 16;
  return (ushort)u;
}
DEVFN float sigmoidf(float x) { return 1.0f / (1.0f + __expf(-x)); }

DEVFN uint pkminu(uint a, uint b) {
  uint r; asm("v_pk_min_u16 %0, %1, %2" : "=v"(r) : "v"(a), "v"(b)); return r;
}
DEVFN uint pkmaxu(uint a, uint b) {
  uint r; asm("v_pk_max_u16 %0, %1, %2" : "=v"(r) : "v"(a), "v"(b)); return r;
}
DEVFN uint ror16(uint x) { return (x >> 16) | (x << 16); }

// ---------------------------------------------------------------------------
// Kernel 1: y_h = h_en_w @ x, y_z = z_en_w @ x  (per pixel 64x64 matvec)
// x NCHW fp32 -> ypack NHWC (dword per (pix,c): lo16 bf16(y_h), hi16 bf16(y_z))
// PLUS fused per-tile pooling partials (fp32): part[b][tile][stat][c]
// grid 512 = b(2) x tile(256); block 256
// ---------------------------------------------------------------------------
__global__ __launch_bounds__(256) void k_conv(const float* __restrict__ x,
                                              const float* __restrict__ wh,
                                              const float* __restrict__ wz,
                                              uint* __restrict__ ypack,
                                              float* __restrict__ part) {
  __shared__ __align__(16) float xt[64][66];
  __shared__ __align__(16) float wls[2][64][64];  // [hz][c][o] transposed
  const int tid = threadIdx.x;
  const int b = blockIdx.x >> 8;
  const int tile = blockIdx.x & 255;
  const int pix0 = tile * 64;

  for (int idx = tid; idx < 4096; idx += 256) {
    int o = idx >> 6, c = idx & 63;
    wls[0][c][o] = wh[idx];
    wls[1][c][o] = wz[idx];
  }
  const float* xb = x + ((size_t)b << 20);  // b * 64*16384
  for (int idx = tid; idx < 4096; idx += 256) {
    int c = idx >> 6, p = idx & 63;
    xt[c][p] = xb[c * 16384 + pix0 + p];
  }
  __syncthreads();

  const int p = tid & 63, og = tid >> 6, o0 = og * 16;
  float fh[16], fz[16];
#pragma unroll
  for (int j = 0; j < 16; ++j) { fh[j] = 0.0f; fz[j] = 0.0f; }

  for (int c = 0; c < 64; ++c) {
    float xv = xt[c][p];
    const float4* whp = (const float4*)&wls[0][c][o0];
    const float4* wzp = (const float4*)&wls[1][c][o0];
#pragma unroll
    for (int jj = 0; jj < 4; ++jj) {
      float4 a = whp[jj], bb = wzp[jj];
      fh[jj * 4 + 0] += xv * a.x; fh[jj * 4 + 1] += xv * a.y;
      fh[jj * 4 + 2] += xv * a.z; fh[jj * 4 + 3] += xv * a.w;
      fz[jj * 4 + 0] += xv * bb.x; fz[jj * 4 + 1] += xv * bb.y;
      fz[jj * 4 + 2] += xv * bb.z; fz[jj * 4 + 3] += xv * bb.w;
    }
  }
  uint* orow = ypack + ((size_t)(b * 16384 + pix0 + p)) * 64 + o0;
#pragma unroll
  for (int jj = 0; jj < 4; ++jj) {
    uint4 pk;
    pk.x = (uint)f2bf(fh[jj * 4 + 0]) | ((uint)f2bf(fz[jj * 4 + 0]) << 16);
    pk.y = (uint)f2bf(fh[jj * 4 + 1]) | ((uint)f2bf(fz[jj * 4 + 1]) << 16);
    pk.z = (uint)f2bf(fh[jj * 4 + 2]) | ((uint)f2bf(fz[jj * 4 + 2]) << 16);
    pk.w = (uint)f2bf(fh[jj * 4 + 3]) | ((uint)f2bf(fz[jj * 4 + 3]) << 16);
    ((uint4*)orow)[jj] = pk;
  }

  // ---- fused pooling partials (fp32, exact y before bf16 rounding) ----
  __syncthreads();
  float* xtA = &xt[0][0];
  float* ztA = &wls[0][0][0];
#pragma unroll
  for (int j = 0; j < 16; ++j) {
    xtA[(o0 + j) * 66 + p] = fh[j];
    ztA[(o0 + j) * 66 + p] = fz[j];
  }
  __syncthreads();
  if (tid < 128) {
    const int o = tid & 63;
    const float* src = (tid < 64) ? xtA : ztA;
    float sm = 0.0f, mx = -1e30f;
#pragma unroll 8
    for (int pp = 0; pp < 64; ++pp) {
      float v = src[o * 66 + pp];
      sm += v; mx = fmaxf(mx, v);
    }
    float* pb = part + ((size_t)(b * 256 + tile) * 4) * 64;
    const int st = (tid < 64) ? 0 : 2;
    pb[st * 64 + o] = sm;
    pb[(st + 1) * 64 + o] = mx;
  }
}

// ---------------------------------------------------------------------------
// Kernel 2: SE attention scalars. grid 4 = hz(2) x b(2); block 256.
// ---------------------------------------------------------------------------
__global__ __launch_bounds__(256) void k_attn(const float* __restrict__ part,
                       const float* __restrict__ hsw, const float* __restrict__ zsw,
                       const float* __restrict__ hew, const float* __restrict__ zew,
                       float* __restrict__ attnb) {
  __shared__ float psum[4][64];
  __shared__ float pmax[4][64];
  __shared__ float pooled[128];
  __shared__ float hdn[128];
  const int tid = threadIdx.x;
  const int hz = blockIdx.x >> 1, bb = blockIdx.x & 1;
  const int g = tid >> 6, c = tid & 63;

  {
    float sm = 0.0f, mx = -1e30f;
    const float* pb = part + ((size_t)(bb * 256 + g * 64) * 4) * 64;
    for (int tt = 0; tt < 64; ++tt) {
      sm += pb[(size_t)tt * 256 + 2 * hz * 64 + c];
      mx = fmaxf(mx, pb[(size_t)tt * 256 + (2 * hz + 1) * 64 + c]);
    }
    psum[g][c] = sm; pmax[g][c] = mx;
  }
  __syncthreads();
  if (tid < 64) {
    float sm = psum[0][c] + psum[1][c] + psum[2][c] + psum[3][c];
    float mx = fmaxf(fmaxf(pmax[0][c], pmax[1][c]), fmaxf(pmax[2][c], pmax[3][c]));
    pooled[c] = sm * (1.0f / 16384.0f);
    pooled[64 + c] = mx;
  }
  __syncthreads();
  if (tid < 128) {
    const float* sw = hz ? zsw : hsw;
    float acc = 0.0f;
    for (int cc = 0; cc < 128; ++cc) acc += pooled[cc] * sw[tid * 128 + cc];
    hdn[tid] = fmaxf(acc, 0.0f);
  }
  __syncthreads();
  const float* ew = hz ? zew : hew;
  for (int o2 = tid; o2 < 512; o2 += 256) {
    const int gb = (o2 >> 6) * 16;
    float acc = 0.0f;
#pragma unroll
    for (int vv = 0; vv < 16; ++vv) acc += hdn[gb + vv] * ew[o2 * 16 + vv];
    attnb[(hz * 2 + bb) * 512 + o2] = sigmoidf(acc);
  }
}

// ---------------------------------------------------------------------------
// Kernel 3: all 8 directional GRU scans. One wave per chain; lane = channel.
// Depth-8 software-pipelined loads. grid 766 x 256 (4 waves/block)
// ---------------------------------------------------------------------------
__global__ __launch_bounds__(256) void k_scan(const uint* __restrict__ ypack,
                                              const float* __restrict__ attnb,
                                              const float* __restrict__ h0,
                                              ushort* __restrict__ xcat) {
  const int wid = blockIdx.x * 4 + (threadIdx.x >> 6);
  const int lane = threadIdx.x & 63;
  int i, b, s;
  if (wid < 2040) {
    i = wid / 510;
    int r = wid - i * 510;
    b = (r >= 255) ? 1 : 0;
    s = r - b * 255;
  } else {
    int w2 = wid - 2040;
    i = 4 + (w2 >> 8);
    int r = w2 & 255;
    b = r >> 7;
    s = r & 127;
  }
  int h0s, w0s, dh, dw, L;
  switch (i) {
    case 0: dh = 1;  dw = 1;
      if (s < 128) { h0s = s; w0s = 0; L = 128 - s; } else { h0s = 0; w0s = s - 127; L = 255 - s; }
      break;
    case 1: dh = 1;  dw = -1;
      if (s < 128) { h0s = 0; w0s = s; L = s + 1; } else { h0s = s - 127; w0s = 127; L = 255 - s; }
      break;
    case 2: dh = -1; dw = 1;
      if (s < 128) { h0s = s; w0s = 0; L = s + 1; } else { h0s = 127; w0s = s - 127; L = 255 - s; }
      break;
    case 3: dh = -1; dw = -1;
      if (s < 128) { h0s = 127; w0s = s; L = s + 1; } else { h0s = s - 128; w0s = 127; L = s - 127; }
      break;
    case 4: dh = 1;  dw = 0;  h0s = 0;   w0s = s; L = 128; break;
    case 5: dh = -1; dw = 0;  h0s = 127; w0s = s; L = 128; break;
    case 6: dh = 0;  dw = 1;  h0s = s;   w0s = 0; L = 128; break;
    default: dh = 0; dw = -1; h0s = s;   w0s = 127; L = 128; break;
  }
  const float ah = attnb[b * 512 + i * 64 + lane];
  const float az = attnb[1024 + b * 512 + i * 64 + lane];
  float hp = h0[i * 64 + lane];

  const int pos = b * 16384 + h0s * 128 + w0s;
  const int dstep = dh * 128 + dw;
  const uint* yp = ypack + (size_t)pos * 64 + lane;
  ushort* xp = xcat + (size_t)pos * 512 + i * 64 + lane;
  const ptrdiff_t ystep = (ptrdiff_t)dstep * 64;
  const ptrdiff_t xstep = (ptrdiff_t)dstep * 512;

#define PROC1(u) { float yh = bf2f((u) & 0xffffu), yz = bf2f((u) >> 16); \
                   float zt = sigmoidf(yz * az);                          \
                   hp = fmaf(zt, fmaf(yh, ah, -hp), hp);                  \
                   *xp = f2bf(hp); xp += xstep; }

  uint c0 = 0, c1 = 0, c2 = 0, c3 = 0, c4 = 0, c5 = 0, c6 = 0, c7 = 0;
  c0 = yp[0];
  if (1 < L) c1 = yp[ystep];
  if (2 < L) c2 = yp[2 * ystep];
  if (3 < L) c3 = yp[3 * ystep];
  if (4 < L) c4 = yp[4 * ystep];
  if (5 < L) c5 = yp[5 * ystep];
  if (6 < L) c6 = yp[6 * ystep];
  if (7 < L) c7 = yp[7 * ystep];

  for (int base = 0; base < L; base += 8) {
    uint b0 = c0, b1 = c1, b2 = c2, b3 = c3, b4 = c4, b5 = c5, b6 = c6, b7 = c7;
    const uint* ypn = yp + (ptrdiff_t)(base + 8) * ystep;
    if (base + 8 < L) {
      c0 = ypn[0];
      if (base + 9  < L) c1 = ypn[ystep];
      if (base + 10 < L) c2 = ypn[2 * ystep];
      if (base + 11 < L) c3 = ypn[3 * ystep];
      if (base + 12 < L) c4 = ypn[4 * ystep];
      if (base + 13 < L) c5 = ypn[5 * ystep];
      if (base + 14 < L) c6 = ypn[6 * ystep];
      if (base + 15 < L) c7 = ypn[7 * ystep];
    }
    PROC1(b0);
    if (base + 1 < L) PROC1(b1);
    if (base + 2 < L) PROC1(b2);
    if (base + 3 < L) PROC1(b3);
    if (base + 4 < L) PROC1(b4);
    if (base + 5 < L) PROC1(b5);
    if (base + 6 < L) PROC1(b6);
    if (base + 7 < L) PROC1(b7);
  }
#undef PROC1
}

// ---------------------------------------------------------------------------
// Kernel 4: per-pixel sort(512) + grouped-conv attention + weighted sum.
// PACKED-BF16 SORT: values are bf16; map each to an order-preserving u16 key
// (key = x ^ (0x8000 | sign*0x7FFF)), pack 2/dword -> 4 dwords/lane.
// Bitonic over e = lane*8 + p*2 + half: direction bit (e&k) is NEVER the half
// bit (k>=2), so packed v_pk_min/max_u16 handles both halves per op.
// Cross-lane shuffles halve (168 -> 84 DS/px); sort regs halve.
// w2/w3 packed bf16x2 in registers; w4 bf16x2 in LDS.
// __launch_bounds__(256,3): VGPR cap 85 -> 3 waves/SIMD (empirical model:
// waves/SIMD = floor(256/VGPR); 104-120 gave 2, 64 gave 4).
// tb1 rows wave-private; no in-loop barriers (HW-validated r4/r7/r9).
// ---------------------------------------------------------------------------
__global__ __launch_bounds__(256, 3) void k_final(const ushort* __restrict__ xcat,
                                                  const float* __restrict__ a_w1,
                                                  const float* __restrict__ a_w2,
                                                  const float* __restrict__ a_w3,
                                                  const float* __restrict__ a_w4,
                                                  float* __restrict__ out) {
  __shared__ __align__(16) float w1s[128 * 32];
  __shared__ uint w4p[32 * 64];     // [rr*4+kp][lane] packed bf16x2
  __shared__ float tb1[4][128];
  __shared__ __align__(16) float otile[16][68];

  const int tid = threadIdx.x;
  const int lane = tid & 63;
  const int wslot = tid >> 6;
  const int b = blockIdx.x >> 10;
  const int tile = blockIdx.x & 1023;
  const int pix0 = tile * 16;

  // stage a_w1 with swizzle: slot = o*32 + ((ci + (o>>2)) & 31)
  for (int idx = tid; idx < 4096; idx += 256) {
    int o = idx >> 5, ci = idx & 31;
    w1s[o * 32 + ((ci + (o >> 2)) & 31)] = a_w1[idx];
  }
  // stage a_w4 as bf16x2, lane-major
  for (int idx = tid; idx < 2048; idx += 256) {
    int rk2 = idx >> 6, l = idx & 63;
    int rr = rk2 >> 2, kp = rk2 & 3;
    const float* src = a_w4 + ((l * 8 + rr) * 8 + 2 * kp);
    w4p[rk2 * 64 + l] = (uint)f2bf(src[0]) | ((uint)f2bf(src[1]) << 16);
  }

  // per-lane packed bf16 weights for gconv2/3: lo = a-path, hi = b-path
  uint w2p[8], w3p[8];
#pragma unroll
  for (int kk = 0; kk < 8; ++kk) {
    w2p[kk] = (uint)f2bf(a_w2[lane * 8 + kk]) | ((uint)f2bf(a_w2[512 + lane * 8 + kk]) << 16);
    w3p[kk] = (uint)f2bf(a_w3[lane * 8 + kk]) | ((uint)f2bf(a_w3[512 + lane * 8 + kk]) << 16);
  }
  __syncthreads();

  const int q = lane >> 2, m4 = lane & 3;
  const int base1 = 64 * ((lane >> 3) & 1) + (lane >> 4);
  const int base3 = 64 * ((lane >> 2) & 1) + (lane >> 3);

  for (int it = 0; it < 4; ++it) {
    const int px = wslot * 4 + it;
    const int pix = pix0 + px;

    uint vp[4], s[4];
    {
      const uint4 pk = *(const uint4*)(xcat + (((size_t)(b * 16384 + pix)) << 9) + lane * 8);
      vp[0] = pk.x; vp[1] = pk.y; vp[2] = pk.z; vp[3] = pk.w;
    }
    // map bf16 -> order-preserving u16 keys (packed)
#pragma unroll
    for (int p = 0; p < 4; ++p) {
      uint sgn = (vp[p] >> 15) & 0x00010001u;
      s[p] = vp[p] ^ (0x80008000u | (sgn * 0x7FFFu));
    }

    // ---- packed bitonic sort, ascending over e = lane*8 + p*2 + half ----
#pragma unroll
    for (int k = 2; k <= 512; k <<= 1) {
      // cross-lane stages (j >= 8, k >= 16)
#pragma unroll
      for (int j = k >> 1; j >= 8; j >>= 1) {
        const int m = j >> 3;
        const bool asc = (lane & (k >> 3)) == 0;
        const bool takeMin = ((lane & m) != 0) != asc;
#pragma unroll
        for (int p = 0; p < 4; ++p) {
          uint o = __shfl_xor(s[p], m, 64);
          uint mn = pkminu(s[p], o), mx = pkmaxu(s[p], o);
          s[p] = takeMin ? mn : mx;
        }
      }
      // j == 4 (dword pairs (0,2),(1,3)); only for k >= 8; dir lane-uniform
      if (k >= 8) {
        const bool asc = (lane & (k >> 3)) == 0;
        uint mn0 = pkminu(s[0], s[2]), mx0 = pkmaxu(s[0], s[2]);
        uint mn1 = pkminu(s[1], s[3]), mx1 = pkmaxu(s[1], s[3]);
        s[0] = asc ? mn0 : mx0;  s[2] = asc ? mx0 : mn0;
        s[1] = asc ? mn1 : mx1;  s[3] = asc ? mx1 : mn1;
      }
      // j == 2 (dword pairs (0,1),(2,3))
      if (k >= 8) {
        const bool asc = (lane & (k >> 3)) == 0;
        uint mn0 = pkminu(s[0], s[1]), mx0 = pkmaxu(s[0], s[1]);
        uint mn1 = pkminu(s[2], s[3]), mx1 = pkmaxu(s[2], s[3]);
        s[0] = asc ? mn0 : mx0;  s[1] = asc ? mx0 : mn0;
        s[2] = asc ? mn1 : mx1;  s[3] = asc ? mx1 : mn1;
      } else if (k == 4) {
        // dir from e&4 = p bit1: d0,d1 asc; d2,d3 desc (compile-time)
        uint mn0 = pkminu(s[0], s[1]), mx0 = pkmaxu(s[0], s[1]);
        uint mn1 = pkminu(s[2], s[3]), mx1 = pkmaxu(s[2], s[3]);
        s[0] = mn0; s[1] = mx0;
        s[2] = mx1; s[3] = mn1;
      }
      // j == 1 (within dword)
      if (k >= 8) {
        const bool asc = (lane & (k >> 3)) == 0;
#pragma unroll
        for (int p = 0; p < 4; ++p) {
          uint t = ror16(s[p]);
          uint mn = pkminu(s[p], t), mx = pkmaxu(s[p], t);
          uint ra = (mn & 0x0000FFFFu) | (mx & 0xFFFF0000u);
          s[p] = asc ? ra : ror16(ra);
        }
      } else if (k == 4) {
        // e&4 = p bit1: d0,d1 asc; d2,d3 desc
#pragma unroll
        for (int p = 0; p < 4; ++p) {
          uint t = ror16(s[p]);
          uint mn = pkminu(s[p], t), mx = pkmaxu(s[p], t);
          uint ra = (mn & 0x0000FFFFu) | (mx & 0xFFFF0000u);
          s[p] = (p < 2) ? ra : ror16(ra);
        }
      } else {  // k == 2: e&2 = p bit0: d0,d2 asc; d1,d3 desc
#pragma unroll
        for (int p = 0; p < 4; ++p) {
          uint t = ror16(s[p]);
          uint mn = pkminu(s[p], t), mx = pkmaxu(s[p], t);
          uint ra = (mn & 0x0000FFFFu) | (mx & 0xFFFF0000u);
          s[p] = ((p & 1) == 0) ? ra : ror16(ra);
        }
      }
    }

    // unmap keys -> bf16 (packed), then unpack both v and s to f32
    float vf[8], sf[8];
#pragma unroll
    for (int p = 0; p < 4; ++p) {
      uint ns = ((~s[p]) >> 15) & 0x00010001u;
      uint sb = s[p] ^ (0x80008000u | (ns * 0x7FFFu));
      sf[2 * p]     = __uint_as_float(sb << 16);
      sf[2 * p + 1] = __uint_as_float(sb & 0xFFFF0000u);
      vf[2 * p]     = __uint_as_float(vp[p] << 16);
      vf[2 * p + 1] = __uint_as_float(vp[p] & 0xFFFF0000u);
    }

    // ---- gconv1 (1024 -> 128, groups 32): quad-cooperative ----
    float pa[4], pb[4];
#pragma unroll
    for (int u = 0; u < 4; ++u) {
      const float* wV = &w1s[(4 * q + u) * 32];
      const float* wS = &w1s[(64 + 4 * q + u) * 32];
      float aV = 0.0f, aS = 0.0f;
#pragma unroll
      for (int r = 0; r < 8; ++r) {
        const int ci = m4 * 8 + r;
        aV += vf[r] * wV[(ci + q) & 31];
        aS += sf[r] * wS[(ci + q + 16) & 31];
      }
      pa[u] = aV; pb[u] = aS;
    }
#pragma unroll
    for (int u = 0; u < 4; ++u) {
      pa[u] += __shfl_xor(pa[u], 1, 64);
      pa[u] += __shfl_xor(pa[u], 2, 64);
      pb[u] += __shfl_xor(pb[u], 1, 64);
      pb[u] += __shfl_xor(pb[u], 2, 64);
    }
    const float t1a = (m4 == 0) ? pa[0] : (m4 == 1) ? pa[1] : (m4 == 2) ? pa[2] : pa[3];
    const float t1b = (m4 == 0) ? pb[0] : (m4 == 1) ? pb[1] : (m4 == 2) ? pb[2] : pb[3];

    tb1[wslot][lane] = t1a;
    tb1[wslot][64 + lane] = t1b;

    // ---- gconv2 (shuffle16 then 128 -> 128, groups 16), bf16 weights ----
    float a2 = 0.0f, b2 = 0.0f;
#pragma unroll
    for (int kk = 0; kk < 8; ++kk) {
      float wa = __uint_as_float(w2p[kk] << 16);
      float wb = __uint_as_float(w2p[kk] & 0xFFFF0000u);
      a2 += tb1[wslot][base1 + 8 * kk] * wa;
      b2 += tb1[wslot][base1 + 8 * kk + 4] * wb;
    }
    tb1[wslot][lane] = a2;        // same-wave DS ordering: reads precede writes
    tb1[wslot][64 + lane] = b2;

    // ---- gconv3 + relu ----
    float a3 = 0.0f, b3 = 0.0f;
#pragma unroll
    for (int kk = 0; kk < 8; ++kk) {
      float wa = __uint_as_float(w3p[kk] << 16);
      float wb = __uint_as_float(w3p[kk] & 0xFFFF0000u);
      a3 += tb1[wslot][base1 + 8 * kk] * wa;
      b3 += tb1[wslot][base1 + 8 * kk + 4] * wb;
    }
    tb1[wslot][lane] = fmaxf(a3, 0.0f);
    tb1[wslot][64 + lane] = fmaxf(b3, 0.0f);

    // ---- gconv4 (128 -> 512, groups 16) + sigmoid + weighted channel-sum ----
    float in4[8];
#pragma unroll
    for (int kk = 0; kk < 8; ++kk) in4[kk] = tb1[wslot][base3 + 8 * kk];

    float prod[8];
#pragma unroll
    for (int rr = 0; rr < 8; ++rr) {
      float acc = 0.0f;
#pragma unroll
      for (int kp = 0; kp < 4; ++kp) {
        uint pw = w4p[(rr * 4 + kp) * 64 + lane];
        float wlo = __uint_as_float(pw << 16);
        float whi = __uint_as_float(pw & 0xffff0000u);
        acc += in4[2 * kp] * wlo + in4[2 * kp + 1] * whi;
      }
      prod[rr] = vf[rr] * sigmoidf(acc);
    }
#pragma unroll
    for (int rr = 0; rr < 8; ++rr) {
      prod[rr] += __shfl_xor(prod[rr], 8, 64);
      prod[rr] += __shfl_xor(prod[rr], 16, 64);
      prod[rr] += __shfl_xor(prod[rr], 32, 64);
    }
    if (lane < 8) {
      float4* dst = (float4*)&otile[px][lane * 8];
      dst[0] = make_float4(prod[0], prod[1], prod[2], prod[3]);
      dst[1] = make_float4(prod[4], prod[5], prod[6], prod[7]);
    }
  }
  __syncthreads();

  // coalesced NCHW store: out[b][c][pix0 + px]
  for (int idx = tid; idx < 1024; idx += 256) {
    int px = idx & 15, c = idx >> 4;
    out[(((size_t)(b * 64 + c)) << 14) + pix0 + px] = otile[px][c];
  }
}

// ---------------------------------------------------------------------------
extern "C" void kernel_launch(void* const* d_in, const int* in_sizes, int n_in,
                              void* d_out, int out_size, void* d_ws, size_t ws_size,
                              hipStream_t stream) {
  const float* x      = (const float*)d_in[0];
  const float* h0     = (const float*)d_in[1];
  const float* h_en_w = (const float*)d_in[2];
  const float* h_s_w  = (const float*)d_in[3];
  const float* h_e_w  = (const float*)d_in[4];
  const float* z_en_w = (const float*)d_in[5];
  const float* z_s_w  = (const float*)d_in[6];
  const float* z_e_w  = (const float*)d_in[7];
  const float* a_w1   = (const float*)d_in[8];
  const float* a_w2   = (const float*)d_in[9];
  const float* a_w3   = (const float*)d_in[10];
  const float* a_w4   = (const float*)d_in[11];
  float* out = (float*)d_out;

  char* ws = (char*)d_ws;
  uint*   ypack = (uint*)ws;                                   // 8 MB
  ushort* xcat  = (ushort*)(ws + ((size_t)8 << 20));           // 32 MB
  float*  part  = (float*)(ws + ((size_t)40 << 20));           // 512 KB
  float*  attnb = (float*)(ws + ((size_t)40 << 20) + (1u << 20));  // 2048 f

  hipLaunchKernelGGL(k_conv, dim3(512), dim3(256), 0, stream, x, h_en_w, z_en_w,
                     ypack, part);
  hipLaunchKernelGGL(k_attn, dim3(4), dim3(256), 0, stream, part, h_s_w, z_s_w,
                     h_e_w, z_e_w, attnb);
  hipLaunchKernelGGL(k_scan, dim3(766), dim3(256), 0, stream, ypack, attnb, h0, xcat);
  hipLaunchKernelGGL(k_final, dim3(2048), dim3(256), 0, stream, xcat, a_w1, a_w2, a_w3,
                     a_w4, out);
}